// Round 1
// baseline (30.040 us; speedup 1.0000x reference)
//
#include <hip/hip_runtime.h>
#include <hip/hip_bf16.h>

// Constants matching the reference
// x: [B, 3, 16, 16] f32 ; lhs: [2, 16, 8] ; rhs: [2, 8, 16] ; W: [1, 3072] ; b: [1]
// out: [B, 1] f32
//
// Algebraic collapse: the whole pipeline is linear in x, so
//   out[b] = dot(x[b] (768 f32), Weff (768 f32)) + bias
// with Weff[ch, r*8+p, c*8+q] = sum_{P,Q} lhs[r,P,p] * rhs[c,q,Q]
//                               * W[ch*1024 + (r*16+P)*32 + (c*16+Q)]

#define BATCH 32768
#define ROW_F32 768      // 3*16*16 floats per sample
#define ROW_F4 192       // in float4 units

// Kernel 1: build Weff (768 floats) in workspace. One block of 768 threads.
__global__ void build_weff_kernel(const float* __restrict__ lhs,
                                  const float* __restrict__ rhs,
                                  const float* __restrict__ W,
                                  float* __restrict__ weff) {
    int t = threadIdx.x;              // 0..767
    int ch = t >> 8;                  // 0..2
    int rem = t & 255;
    int i = rem >> 4;                 // row in 16x16 compressed, 0..15
    int j = rem & 15;                 // col, 0..15
    int r = i >> 3;                   // row block 0..1
    int p = i & 7;
    int c = j >> 3;                   // col block 0..1
    int q = j & 7;

    const float* Wch = W + ch * 1024;
    float acc = 0.f;
    #pragma unroll
    for (int P = 0; P < 16; ++P) {
        float lv = lhs[r * 128 + P * 8 + p];
        const float* Wrow = Wch + (r * 16 + P) * 32 + c * 16;
        float inner = 0.f;
        #pragma unroll
        for (int Q = 0; Q < 16; ++Q) {
            inner += rhs[c * 128 + q * 16 + Q] * Wrow[Q];
        }
        acc += lv * inner;
    }
    weff[t] = acc;
}

// Kernel 2: one 64-lane wave per batch row; 4 waves (256 threads) per block.
__global__ __launch_bounds__(256) void batched_dot_kernel(
        const float4* __restrict__ x4,
        const float4* __restrict__ w4,
        const float* __restrict__ bptr,
        float* __restrict__ out) {
    int tid = threadIdx.x;
    int lane = tid & 63;
    int row = blockIdx.x * 4 + (tid >> 6);

    const float4* xr = x4 + (size_t)row * ROW_F4;
    float acc = 0.f;
    #pragma unroll
    for (int k = 0; k < 3; ++k) {
        float4 xv = xr[lane + k * 64];   // coalesced: 64 lanes x 16B contiguous
        float4 wv = w4[lane + k * 64];   // L1-resident (3 KB total)
        acc += xv.x * wv.x + xv.y * wv.y + xv.z * wv.z + xv.w * wv.w;
    }
    // wave-64 reduction
    #pragma unroll
    for (int off = 32; off; off >>= 1) acc += __shfl_down(acc, off);

    if (lane == 0) out[row] = acc + bptr[0];
}

extern "C" void kernel_launch(void* const* d_in, const int* in_sizes, int n_in,
                              void* d_out, int out_size, void* d_ws, size_t ws_size,
                              hipStream_t stream) {
    const float* x   = (const float*)d_in[0];   // [32768, 3, 16, 16]
    const float* lhs = (const float*)d_in[1];   // [2, 16, 8]
    const float* rhs = (const float*)d_in[2];   // [2, 8, 16]
    const float* W   = (const float*)d_in[3];   // [1, 3072]
    const float* b   = (const float*)d_in[4];   // [1]
    float* out = (float*)d_out;                 // [32768]

    float* weff = (float*)d_ws;                 // 768 floats = 3 KB

    build_weff_kernel<<<1, 768, 0, stream>>>(lhs, rhs, W, weff);

    batched_dot_kernel<<<BATCH / 4, 256, 0, stream>>>(
        (const float4*)x, (const float4*)weff, b, out);
}

// Round 2
// 27.778 us; speedup vs baseline: 1.0815x; 1.0815x over previous
//
#include <hip/hip_runtime.h>
#include <hip/hip_bf16.h>

// x: [32768, 3, 16, 16] f32 ; lhs: [2, 16, 8] ; rhs: [2, 8, 16] ; W: [1, 3072] ; b: [1]
// out: [32768] f32
//
// Algebraic collapse (verified R1, absmax 2.4e-4):
//   out[b] = dot(x[b] (768 f32), Weff (768 f32)) + bias
//   Weff[ch, r*8+p, c*8+q] = sum_{P,Q} lhs[r,P,p] * rhs[c,q,Q]
//                            * W[ch*1024 + (r*16+P)*32 + (c*16+Q)]
//
// Fused single kernel: each block computes Weff redundantly (two-stage
// contraction in LDS, 144 FMA/thread, inputs L2-cached) while the first
// x-tile loads are in flight, then streams 32 rows/block.

#define BATCH 32768
#define ROW_F4 192              // 768 floats per sample in float4 units
#define ROWS_PER_BLOCK 32
#define GRID_BLOCKS (BATCH / ROWS_PER_BLOCK)   // 1024

__device__ __forceinline__ float dot4(const float4& a, const float4& b) {
    return a.x * b.x + a.y * b.y + a.z * b.z + a.w * b.w;
}

// Merged 4-row wave64 reduction: 10 shfl instead of 24.
// On exit, lane L holds the full sum for row (L&3); lanes 0..3 store.
__device__ __forceinline__ void reduce4_store(float a0, float a1, float a2, float a3,
                                              int lane, float* __restrict__ outp,
                                              float bias) {
    a0 += __shfl_xor(a0, 1);
    a1 += __shfl_xor(a1, 1);
    a2 += __shfl_xor(a2, 1);
    a3 += __shfl_xor(a3, 1);
    float b0 = (lane & 1) ? a1 : a0;   // holds row (lane&1), pair-summed
    float b1 = (lane & 1) ? a3 : a2;   // holds row 2+(lane&1)
    b0 += __shfl_xor(b0, 2);
    b1 += __shfl_xor(b1, 2);
    float c = (lane & 2) ? b1 : b0;    // holds row (lane&3), nibble-summed
    c += __shfl_xor(c, 4);
    c += __shfl_xor(c, 8);
    c += __shfl_xor(c, 16);
    c += __shfl_xor(c, 32);
    if (lane < 4) outp[lane] = c + bias;
}

__global__ __launch_bounds__(256, 4) void fused_compressor_kernel(
        const float4* __restrict__ x4,
        const float* __restrict__ lhs,
        const float* __restrict__ rhs,
        const float* __restrict__ W,
        const float* __restrict__ bptr,
        float* __restrict__ out) {
    __shared__ float tmp[1536];                 // [ch][R(32)][j(16)]
    __shared__ __align__(16) float weff[768];   // [ch][i(16)][j(16)]

    const int tid  = threadIdx.x;
    const int lane = tid & 63;
    const int w    = tid >> 6;

    const int row0 = blockIdx.x * ROWS_PER_BLOCK + w * 8;   // 8 rows per wave

    // ---- prefetch iteration-0 x into registers (independent of LDS phases;
    //      HBM latency hides the Weff contraction below) ----
    const float4* xr = x4 + (size_t)row0 * ROW_F4 + lane;
    float4 xv[4][3];
    #pragma unroll
    for (int rr = 0; rr < 4; ++rr)
        #pragma unroll
        for (int k = 0; k < 3; ++k)
            xv[rr][k] = xr[rr * ROW_F4 + k * 64];

    // ---- stage A: tmp[ch,R,j] = sum_Q rhs[c,q,Q] * W[ch*1024 + R*32 + c*16 + Q]
    //      (j = c*8+q), 1536 outputs, 6 per thread ----
    #pragma unroll
    for (int s = 0; s < 6; ++s) {
        int idx = tid + (s << 8);           // 0..1535
        int ch  = idx >> 9;
        int rem = idx & 511;
        int R   = rem >> 4;
        int j   = rem & 15;
        int c   = j >> 3;
        int q   = j & 7;
        const float* rp = rhs + c * 128 + q * 16;
        const float* wp = W + ch * 1024 + R * 32 + c * 16;
        float acc = 0.f;
        #pragma unroll
        for (int Q = 0; Q < 16; ++Q) acc += rp[Q] * wp[Q];
        tmp[idx] = acc;
    }
    __syncthreads();

    // ---- stage B: weff[ch,i,j] = sum_P lhs[r*128 + P*8 + p] * tmp[ch*512 + (r*16+P)*16 + j]
    //      768 outputs, 3 per thread ----
    #pragma unroll
    for (int s = 0; s < 3; ++s) {
        int idx = tid + (s << 8);           // 0..767
        int ch  = idx >> 8;                 // == s (tid < 256)
        int rem = idx & 255;
        int i   = rem >> 4;
        int j   = rem & 15;
        int r   = i >> 3;
        int p   = i & 7;
        const float* lp = lhs + r * 128 + p;
        const float* tp = tmp + ch * 512 + r * 256 + j;
        float acc = 0.f;
        #pragma unroll
        for (int P = 0; P < 16; ++P) acc += lp[P * 8] * tp[P * 16];
        weff[idx] = acc;
    }
    __syncthreads();

    // ---- per-lane weight fragment (register-cached for all 8 rows) ----
    const float4* w4 = reinterpret_cast<const float4*>(weff);
    const float4 wv0 = w4[lane];
    const float4 wv1 = w4[lane + 64];
    const float4 wv2 = w4[lane + 128];
    const float  bias = bptr[0];

    // ---- iteration 0 (prefetched) ----
    {
        float a0 = dot4(xv[0][0], wv0) + dot4(xv[0][1], wv1) + dot4(xv[0][2], wv2);
        float a1 = dot4(xv[1][0], wv0) + dot4(xv[1][1], wv1) + dot4(xv[1][2], wv2);
        float a2 = dot4(xv[2][0], wv0) + dot4(xv[2][1], wv1) + dot4(xv[2][2], wv2);
        float a3 = dot4(xv[3][0], wv0) + dot4(xv[3][1], wv1) + dot4(xv[3][2], wv2);
        reduce4_store(a0, a1, a2, a3, lane, out + row0, bias);
    }

    // ---- iteration 1 (rows row0+4 .. row0+7) ----
    {
        const float4* xr1 = xr + 4 * ROW_F4;
        float4 yv[4][3];
        #pragma unroll
        for (int rr = 0; rr < 4; ++rr)
            #pragma unroll
            for (int k = 0; k < 3; ++k)
                yv[rr][k] = xr1[rr * ROW_F4 + k * 64];
        float a0 = dot4(yv[0][0], wv0) + dot4(yv[0][1], wv1) + dot4(yv[0][2], wv2);
        float a1 = dot4(yv[1][0], wv0) + dot4(yv[1][1], wv1) + dot4(yv[1][2], wv2);
        float a2 = dot4(yv[2][0], wv0) + dot4(yv[2][1], wv1) + dot4(yv[2][2], wv2);
        float a3 = dot4(yv[3][0], wv0) + dot4(yv[3][1], wv1) + dot4(yv[3][2], wv2);
        reduce4_store(a0, a1, a2, a3, lane, out + row0 + 4, bias);
    }
}

extern "C" void kernel_launch(void* const* d_in, const int* in_sizes, int n_in,
                              void* d_out, int out_size, void* d_ws, size_t ws_size,
                              hipStream_t stream) {
    const float* x   = (const float*)d_in[0];   // [32768, 3, 16, 16]
    const float* lhs = (const float*)d_in[1];   // [2, 16, 8]
    const float* rhs = (const float*)d_in[2];   // [2, 8, 16]
    const float* W   = (const float*)d_in[3];   // [1, 3072]
    const float* b   = (const float*)d_in[4];   // [1]
    float* out = (float*)d_out;                 // [32768]

    fused_compressor_kernel<<<GRID_BLOCKS, 256, 0, stream>>>(
        (const float4*)x, lhs, rhs, W, b, out);
}

// Round 3
// 24.852 us; speedup vs baseline: 1.2088x; 1.1177x over previous
//
#include <hip/hip_runtime.h>
#include <hip/hip_bf16.h>

// x: [32768, 3, 16, 16] f32 ; lhs: [2, 16, 8] ; rhs: [2, 8, 16] ; W: [1, 3072] ; b: [1]
// out: [32768] f32
//
// Algebraic collapse (verified R1/R2, absmax 2.4e-4):
//   out[b] = dot(x[b] (768 f32), Weff (768 f32)) + bias
//   Weff[ch, r*8+p, c*8+q] = sum_{P,Q} lhs[r,P,p] * rhs[c,q,Q]
//                            * W[ch*1024 + (r*16+P)*32 + (c*16+Q)]
//
// R3 structure: 2048 blocks x 256 threads, 16 rows/block, 4 rows/wave,
// ONE load batch per wave issued before the (L1/L2-fed) weff contraction.
// Single latency exposure hidden under weff compute; continuous HBM demand
// via async block churn (8 block-rounds per CU).

#define BATCH 32768
#define ROW_F4 192              // 768 floats per sample in float4 units
#define ROWS_PER_BLOCK 16
#define GRID_BLOCKS (BATCH / ROWS_PER_BLOCK)   // 2048

__device__ __forceinline__ float dot4(const float4& a, const float4& b) {
    return a.x * b.x + a.y * b.y + a.z * b.z + a.w * b.w;
}

// Merged 4-row wave64 reduction: 10 shfl instead of 24.
// On exit lanes 0..3 hold full sums for rows 0..3 and store.
__device__ __forceinline__ void reduce4_store(float a0, float a1, float a2, float a3,
                                              int lane, float* __restrict__ outp,
                                              float bias) {
    a0 += __shfl_xor(a0, 1);
    a1 += __shfl_xor(a1, 1);
    a2 += __shfl_xor(a2, 1);
    a3 += __shfl_xor(a3, 1);
    float b0 = (lane & 1) ? a1 : a0;   // row (lane&1)
    float b1 = (lane & 1) ? a3 : a2;   // row 2+(lane&1)
    b0 += __shfl_xor(b0, 2);
    b1 += __shfl_xor(b1, 2);
    float c = (lane & 2) ? b1 : b0;    // row (lane&3)
    c += __shfl_xor(c, 4);
    c += __shfl_xor(c, 8);
    c += __shfl_xor(c, 16);
    c += __shfl_xor(c, 32);
    if (lane < 4) outp[lane] = c + bias;
}

__global__ __launch_bounds__(256, 4) void fused_compressor_kernel(
        const float4* __restrict__ x4,
        const float* __restrict__ lhs,
        const float4* __restrict__ rhs4,
        const float4* __restrict__ W4,
        const float* __restrict__ bptr,
        float* __restrict__ out) {
    __shared__ float tmp[1536];                 // [ch][R(32)][j(16)]
    __shared__ __align__(16) float weff[768];   // [ch][i(16)][j(16)]

    const int tid  = threadIdx.x;
    const int lane = tid & 63;
    const int w    = tid >> 6;

    const int row0 = blockIdx.x * ROWS_PER_BLOCK + w * 4;   // 4 rows per wave

    // ---- issue the wave's ONLY x load-batch (12 x 1KB) immediately;
    //      HBM latency hides under the weff contraction below ----
    const float4* xr = x4 + (size_t)row0 * ROW_F4 + lane;
    float4 xv[4][3];
    #pragma unroll
    for (int rr = 0; rr < 4; ++rr)
        #pragma unroll
        for (int k = 0; k < 3; ++k)
            xv[rr][k] = xr[rr * ROW_F4 + k * 64];

    // ---- stage A: tmp[ch,R,j] = sum_Q rhs[c,q,Q] * W[ch*1024 + R*32 + c*16 + Q]
    //      (j = c*8+q), 1536 outputs, 6 per thread, float4-vectorized ----
    #pragma unroll
    for (int s = 0; s < 6; ++s) {
        int idx = tid + (s << 8);           // 0..1535
        int ch  = idx >> 9;
        int rem = idx & 511;
        int R   = rem >> 4;
        int j   = rem & 15;
        int c   = j >> 3;
        int q   = j & 7;
        const float4* rp = rhs4 + c * 32 + q * 4;            // 16 floats
        const float4* wp = W4 + ch * 256 + R * 8 + c * 4;    // 16 floats
        float acc = dot4(rp[0], wp[0]) + dot4(rp[1], wp[1])
                  + dot4(rp[2], wp[2]) + dot4(rp[3], wp[3]);
        tmp[idx] = acc;
    }
    __syncthreads();

    // ---- stage B: weff[ch,i,j] = sum_P lhs[r*128 + P*8 + p] * tmp[ch*512 + (r*16+P)*16 + j]
    //      768 outputs, 3 per thread ----
    #pragma unroll
    for (int s = 0; s < 3; ++s) {
        int idx = tid + (s << 8);           // 0..767
        int ch  = idx >> 8;
        int rem = idx & 255;
        int i   = rem >> 4;
        int j   = rem & 15;
        int r   = i >> 3;
        int p   = i & 7;
        const float* lp = lhs + r * 128 + p;
        const float* tp = tmp + ch * 512 + r * 256 + j;
        float acc = 0.f;
        #pragma unroll
        for (int P = 0; P < 16; ++P) acc += lp[P * 8] * tp[P * 16];
        weff[idx] = acc;
    }
    __syncthreads();

    // ---- per-lane weight fragment ----
    const float4* w4 = reinterpret_cast<const float4*>(weff);
    const float4 wv0 = w4[lane];
    const float4 wv1 = w4[lane + 64];
    const float4 wv2 = w4[lane + 128];
    const float  bias = bptr[0];

    // ---- single compute pass over the prefetched rows ----
    float a0 = dot4(xv[0][0], wv0) + dot4(xv[0][1], wv1) + dot4(xv[0][2], wv2);
    float a1 = dot4(xv[1][0], wv0) + dot4(xv[1][1], wv1) + dot4(xv[1][2], wv2);
    float a2 = dot4(xv[2][0], wv0) + dot4(xv[2][1], wv1) + dot4(xv[2][2], wv2);
    float a3 = dot4(xv[3][0], wv0) + dot4(xv[3][1], wv1) + dot4(xv[3][2], wv2);
    reduce4_store(a0, a1, a2, a3, lane, out + row0, bias);
}

extern "C" void kernel_launch(void* const* d_in, const int* in_sizes, int n_in,
                              void* d_out, int out_size, void* d_ws, size_t ws_size,
                              hipStream_t stream) {
    const float* x   = (const float*)d_in[0];   // [32768, 3, 16, 16]
    const float* lhs = (const float*)d_in[1];   // [2, 16, 8]
    const float* rhs = (const float*)d_in[2];   // [2, 8, 16]
    const float* W   = (const float*)d_in[3];   // [1, 3072]
    const float* b   = (const float*)d_in[4];   // [1]
    float* out = (float*)d_out;                 // [32768]

    fused_compressor_kernel<<<GRID_BLOCKS, 256, 0, stream>>>(
        (const float4*)x, lhs, (const float4*)rhs, (const float4*)W, b, out);
}